// Round 16
// baseline (327.077 us; speedup 1.0000x reference)
//
#include <hip/hip_runtime.h>
#include <hip/hip_bf16.h>

// BoostedCausalAttention: bf16 MFMA pipeline
// B=2 T=2048 D=1024 H=16 DH=64, fp32 in/out, bf16 internal compute.
// R6 589 -> R8 swizzle 475 -> R9 pairing 352.9 -> R13/14 GEMM dbuf ->
// R15 swapped-QK softmax 309.3 (attn 72.0, VALU 39.5, Mfma 9.4).
// Budget now: attn 144us, GEMMs ~130us (qkv ~43 each @ ~600TF).
// R16: (1) qkv GEMMs -> 256^2 tile, TRIPLE-buffered LDS, counted
//   s_waitcnt vmcnt(4) + raw s_barrier (never vmcnt(0) in loop; a
//   __syncthreads would drain the prefetch queue = the known m97 stall).
//   Stage t+2 into buf[(t+2)%3] (= buffer retired at the end of iter t-1,
//   race-free). Slot swizzle ^(row&3) via pre-swizzled GLD16 source.
//   (2) attn: V staged as packed-b32 kv-pairs (16->8 write instrs), dual
//   fp32+bf16 output (corr_cast eliminated, resid_cast loses catb write).

typedef __bf16 bf16x8 __attribute__((ext_vector_type(8)));
typedef float f32x4 __attribute__((ext_vector_type(4)));

__device__ __forceinline__ unsigned short f2bf(float f) {
  union { __hip_bfloat16 h; unsigned short u; } cv;
  cv.h = __float2bfloat16(f);
  return cv.u;
}

#define GLD16(gp, lp) __builtin_amdgcn_global_load_lds(                      \
    (const __attribute__((address_space(1))) void*)(gp),                     \
    (__attribute__((address_space(3))) void*)(lp), 16, 0, 0)

// ---------------- transpose + cast: fp32 [R][C] -> bf16 [C][R] --------------
__global__ __launch_bounds__(256) void transpose_cast(
    const float* __restrict__ in, __hip_bfloat16* __restrict__ out, int R, int C) {
  __shared__ float t[32][33];
  int bx = blockIdx.x * 32, by = blockIdx.y * 32;
  int tx = threadIdx.x, ty = threadIdx.y;
#pragma unroll
  for (int i = 0; i < 32; i += 8)
    t[ty + i][tx] = in[(size_t)(by + ty + i) * C + bx + tx];
  __syncthreads();
#pragma unroll
  for (int i = 0; i < 32; i += 8)
    out[(size_t)(bx + ty + i) * R + by + tx] = __float2bfloat16(t[tx][ty + i]);
}

// ---------------- cast x -> bf16 (vec4) ------------------------------------
__global__ __launch_bounds__(256) void cast_f32_bf16(
    const float* __restrict__ in, __hip_bfloat16* __restrict__ out) {
  size_t e = ((size_t)blockIdx.x * blockDim.x + threadIdx.x) * 4;
  float4 v = *(const float4*)(in + e);
  ushort4 o;
  o.x = f2bf(v.x); o.y = f2bf(v.y); o.z = f2bf(v.z); o.w = f2bf(v.w);
  *(ushort4*)((unsigned short*)out + e) = o;
}

// --- residb = bf16(x - pred)  (catb pred-half now written by attn) ----------
__global__ __launch_bounds__(256) void resid_cast(
    const float* __restrict__ x, const float* __restrict__ pred,
    __hip_bfloat16* __restrict__ residb) {
  size_t e = ((size_t)blockIdx.x * blockDim.x + threadIdx.x) * 4;
  float4 xv = *(const float4*)(x + e);
  float4 pv = *(const float4*)(pred + e);
  ushort4 rb;
  rb.x = f2bf(xv.x - pv.x); rb.y = f2bf(xv.y - pv.y);
  rb.z = f2bf(xv.z - pv.z); rb.w = f2bf(xv.w - pv.w);
  *(ushort4*)((unsigned short*)residb + e) = rb;
}

// ------- bf16 MFMA GEMM, 128x128 tile, BK=32, double-buffered (R13) ---------
// (kept for gate EPI=1 and out-proj EPI=2)
template <int EPI>
__global__ __launch_bounds__(256) void gemm_bf16(
    const __hip_bfloat16* __restrict__ A, const __hip_bfloat16* __restrict__ Bt,
    const float* __restrict__ bias, void* __restrict__ outp,
    const float* __restrict__ aux0, const float* __restrict__ aux1,
    int M, int N, int K) {
  __shared__ __hip_bfloat16 As[2][128 * 32];
  __shared__ __hip_bfloat16 Bs[2][128 * 32];
  const int tid = threadIdx.x;
  const int lane = tid & 63, wid = tid >> 6;
  const int wr = wid >> 1, wc = wid & 1;
  const int lr = lane & 15, lk = (lane >> 4) * 8;
  const size_t brow = (size_t)blockIdx.y * 128, bcol = (size_t)blockIdx.x * 128;
  f32x4 acc[4][4] = {};
#pragma unroll
  for (int r = 0; r < 2; ++r) {
    int c = tid + r * 256;
    GLD16(A + (brow + (size_t)(c >> 2)) * K + (c & 3) * 8, As[0] + c * 8);
    GLD16(Bt + (bcol + (size_t)(c >> 2)) * K + (c & 3) * 8, Bs[0] + c * 8);
  }
  __syncthreads();
  int cur = 0;
  for (int k0 = 0; k0 < K; k0 += 32) {
    const int nxt = cur ^ 1;
    if (k0 + 32 < K) {
#pragma unroll
      for (int r = 0; r < 2; ++r) {
        int c = tid + r * 256;
        GLD16(A + (brow + (size_t)(c >> 2)) * K + k0 + 32 + (c & 3) * 8,
              As[nxt] + c * 8);
        GLD16(Bt + (bcol + (size_t)(c >> 2)) * K + k0 + 32 + (c & 3) * 8,
              Bs[nxt] + c * 8);
      }
    }
    bf16x8 a[4], b[4];
#pragma unroll
    for (int m = 0; m < 4; ++m)
      a[m] = *(const bf16x8*)(As[cur] + (wr * 64 + m * 16 + lr) * 32 + lk);
#pragma unroll
    for (int n = 0; n < 4; ++n)
      b[n] = *(const bf16x8*)(Bs[cur] + (wc * 64 + n * 16 + lr) * 32 + lk);
#pragma unroll
    for (int m = 0; m < 4; ++m)
#pragma unroll
      for (int n = 0; n < 4; ++n)
        acc[m][n] = __builtin_amdgcn_mfma_f32_16x16x32_bf16(a[m], b[n], acc[m][n], 0, 0, 0);
    __syncthreads();
    cur = nxt;
  }
  const int r0 = (lane >> 4) * 4, cn = lane & 15;
#pragma unroll
  for (int m = 0; m < 4; ++m)
#pragma unroll
    for (int n = 0; n < 4; ++n) {
      size_t col = bcol + wc * 64 + n * 16 + cn;
      float bv = bias[col];
#pragma unroll
      for (int j = 0; j < 4; ++j) {
        size_t row = brow + wr * 64 + m * 16 + r0 + j;
        float v = acc[m][n][j] + bv;
        if constexpr (EPI == 1) {
          float g = 1.0f / (1.0f + __expf(-v));
          float val = g * aux0[row * N + col] + aux1[row * N + col];
          ((__hip_bfloat16*)outp)[row * N + col] = __float2bfloat16(val);
        } else if constexpr (EPI == 2) {
          ((float*)outp)[row * N + col] = v;
        } else {
          ((__hip_bfloat16*)outp)[row * N + col] = __float2bfloat16(v);
        }
      }
    }
}

// ------- bf16 MFMA GEMM, 256x256 tile, BK=32, TRIPLE-buffered (R16) ---------
// 512 thr = 8 waves (2M x 4N); per-wave output 128x64 (8x4 frags).
// Counted vmcnt: stage tile t+2 into buf[(t+2)%3] (freed at end of iter t-1),
// wait vmcnt(4) (tile t+1 landed, t+2's 4 still in flight), raw s_barrier.
// Never vmcnt(0) in the main loop. Slot swizzle ^(row&3) via pre-swizzled
// global source (rule #21), read applies same XOR. Out bf16 = acc + bias.
__global__ __launch_bounds__(512) void gemm256_bf16(
    const __hip_bfloat16* __restrict__ A, const __hip_bfloat16* __restrict__ Bt,
    const float* __restrict__ bias, __hip_bfloat16* __restrict__ outp,
    int M, int N, int K) {
  __shared__ __hip_bfloat16 As[3][256 * 32];
  __shared__ __hip_bfloat16 Bs[3][256 * 32];
  const int tid = threadIdx.x;
  const int lane = tid & 63, wid = tid >> 6;
  const int wr = wid >> 2, wc = wid & 3;
  const int lr = lane & 15, lg = lane >> 4;
  const size_t brow = (size_t)blockIdx.y * 256, bcol = (size_t)blockIdx.x * 256;
  f32x4 acc[8][4] = {};

  auto stage = [&](int t, int buf) {
#pragma unroll
    for (int r = 0; r < 2; ++r) {
      int c = tid + r * 512, row = c >> 2, slot = c & 3;
      GLD16(A + (brow + (size_t)row) * K + t * 32 + ((slot ^ (row & 3)) * 8),
            As[buf] + c * 8);
      GLD16(Bt + (bcol + (size_t)row) * K + t * 32 + ((slot ^ (row & 3)) * 8),
            Bs[buf] + c * 8);
    }
  };

  const int nT = K >> 5;
  stage(0, 0);
  stage(1, 1);
  asm volatile("s_waitcnt vmcnt(4)" ::: "memory");  // tile 0 landed
  __builtin_amdgcn_s_barrier();
  int cur = 0;
  for (int t = 0; t < nT; ++t) {
    const int b2 = (cur + 2 >= 3) ? cur - 1 : cur + 2;
    if (t + 2 < nT) stage(t + 2, b2);
    const __hip_bfloat16* Ab = As[cur];
    const __hip_bfloat16* Bb = Bs[cur];
    bf16x8 a[8], b[4];
#pragma unroll
    for (int m = 0; m < 8; ++m) {
      const int row = wr * 128 + m * 16 + lr;
      a[m] = *(const bf16x8*)(Ab + row * 32 + ((lg ^ (row & 3)) * 8));
    }
#pragma unroll
    for (int n = 0; n < 4; ++n) {
      const int row = wc * 64 + n * 16 + lr;
      b[n] = *(const bf16x8*)(Bb + row * 32 + ((lg ^ (row & 3)) * 8));
    }
#pragma unroll
    for (int m = 0; m < 8; ++m)
#pragma unroll
      for (int n = 0; n < 4; ++n)
        acc[m][n] = __builtin_amdgcn_mfma_f32_16x16x32_bf16(a[m], b[n], acc[m][n], 0, 0, 0);
    if (t + 2 < nT) {
      asm volatile("s_waitcnt vmcnt(4)" ::: "memory");  // t+1 landed
    } else {
      asm volatile("s_waitcnt vmcnt(0)" ::: "memory");  // drain tail
    }
    __builtin_amdgcn_s_barrier();
    cur = (cur + 1 >= 3) ? 0 : cur + 1;
  }
  const int r0 = (lane >> 4) * 4, cn = lane & 15;
#pragma unroll
  for (int m = 0; m < 8; ++m)
#pragma unroll
    for (int n = 0; n < 4; ++n) {
      size_t col = bcol + wc * 64 + n * 16 + cn;
      float bv = bias[col];
#pragma unroll
      for (int j = 0; j < 4; ++j) {
        size_t row = brow + wr * 128 + m * 16 + r0 + j;
        outp[row * N + col] = __float2bfloat16(acc[m][n][j] + bv);
      }
    }
}

// ------- causal flash attention V5b (swapped QK^T, b32 V-stage, dual out) ---
// R15-verified structure. V staged as packed-b32 kv-pairs (8 write instrs vs
// 16; same vts logical layout/swizzle, read side unchanged). Dual output:
// fp32 outp (stride 1024) + bf16 outb (stride 2048, +ob_off) for catb.
__global__ __launch_bounds__(256) void attn_kernel(
    const __hip_bfloat16* __restrict__ qkv, float* __restrict__ outp,
    __hip_bfloat16* __restrict__ outb, int ob_off) {
  const int b = blockIdx.z, h = blockIdx.y, qtp = blockIdx.x;
  const int qlo = qtp, qhi = 31 - qtp;
  const int q0lo = qlo * 64, q0hi = qhi * 64;
  __shared__ __hip_bfloat16 ks[2][64 * 64];
  __shared__ __hip_bfloat16 vts[2][64 * 64];  // V^T [dh][kv], swizzled
  __shared__ __hip_bfloat16 qps[8192];        // Q_hi|Q_lo staging -> ps_hi|ps_lo
  const int tid = threadIdx.x, lane = tid & 63, w = tid >> 6;
  const int lr = lane & 15, lg = lane >> 4;
  const int sw = lr & 7;
  const size_t rs = 3072;
  const __hip_bfloat16* qbh = qkv + ((size_t)b * 2048 + q0hi) * rs + h * 64;
  const __hip_bfloat16* qbl = qkv + ((size_t)b * 2048 + q0lo) * rs + h * 64;
  const __hip_bfloat16* kb = qkv + (size_t)b * 2048 * rs + 1024 + h * 64;
  const __hip_bfloat16* vb = qkv + (size_t)b * 2048 * rs + 2048 + h * 64;

  const int vrow2 = tid >> 3, vseg = tid & 7;  // V staging: kv pair, dh seg
  float4 vr0, vr1;
  // ---- prologue: stage Q_hi/Q_lo/K0 (pre-swizzled src), V0 -> regs
#pragma unroll
  for (int r = 0; r < 2; ++r) {
    int c = tid + r * 256, row = c >> 3, p = c & 7;
    GLD16(qbh + (size_t)row * rs + (p ^ (row & 7)) * 8, qps + c * 8);
    GLD16(qbl + (size_t)row * rs + (p ^ (row & 7)) * 8, qps + 4096 + c * 8);
    GLD16(kb + (size_t)row * rs + (p ^ (row & 7)) * 8, ks[0] + c * 8);
  }
  vr0 = *(const float4*)(vb + (size_t)(2 * vrow2) * rs + vseg * 8);
  vr1 = *(const float4*)(vb + (size_t)(2 * vrow2 + 1) * rs + vseg * 8);
  __syncthreads();
  const int qrow = w * 16 + lr;
  const bf16x8 qh0 = *(const bf16x8*)(qps + qrow * 64 + ((lg) ^ (qrow & 7)) * 8);
  const bf16x8 qh1 = *(const bf16x8*)(qps + qrow * 64 + ((4 + lg) ^ (qrow & 7)) * 8);
  const bf16x8 ql0 = *(const bf16x8*)(qps + 4096 + qrow * 64 + ((lg) ^ (qrow & 7)) * 8);
  const bf16x8 ql1 = *(const bf16x8*)(qps + 4096 + qrow * 64 + ((4 + lg) ^ (qrow & 7)) * 8);
  // write V0 (transpose, packed b32 kv-pairs, swizzled)
  {
    const unsigned short* u0 = (const unsigned short*)&vr0;
    const unsigned short* u1 = (const unsigned short*)&vr1;
#pragma unroll
    for (int i = 0; i < 8; ++i) {
      const int dh = vseg * 8 + i;
      const int phys = (vrow2 >> 2) ^ (dh & 7) ^ ((dh >> 3) & 7);
      unsigned int pk = (unsigned int)u0[i] | ((unsigned int)u1[i] << 16);
      *(unsigned int*)(vts[0] + dh * 64 + phys * 8 + 2 * (vrow2 & 3)) = pk;
    }
  }
  __syncthreads();  // Q frags in regs; qps now free for ps

  __hip_bfloat16* psh = qps + w * 1024;         // wave-private, hi tile
  __hip_bfloat16* psl = qps + 4096 + w * 1024;  // wave-private, lo tile
  float m_hi = -1e30f, l_hi = 0.f, m_lo = -1e30f, l_lo = 0.f;
  f32x4 o_hi[4] = {}, o_lo[4] = {};
  int cur = 0;

  auto process = [&](const bf16x8& qa0, const bf16x8& qa1, bool diag,
                     float& m_run, float& l_run, f32x4* o, __hip_bfloat16* psw) {
    f32x4 s4[4] = {};
#pragma unroll
    for (int n = 0; n < 4; ++n) {
      const int kr = n * 16 + lr;
      bf16x8 k0f = *(const bf16x8*)(ks[cur] + kr * 64 + ((lg) ^ sw) * 8);
      bf16x8 k1f = *(const bf16x8*)(ks[cur] + kr * 64 + ((4 + lg) ^ sw) * 8);
      s4[n] = __builtin_amdgcn_mfma_f32_16x16x32_bf16(k0f, qa0, s4[n], 0, 0, 0);
      s4[n] = __builtin_amdgcn_mfma_f32_16x16x32_bf16(k1f, qa1, s4[n], 0, 0, 0);
    }
    float p[4][4];
    float mloc = -1e30f;
#pragma unroll
    for (int n = 0; n < 4; ++n)
#pragma unroll
      for (int j = 0; j < 4; ++j) {
        float v = s4[n][j] * 0.125f;
        if (diag && (n * 16 + lg * 4 + j) > (w * 16 + lr)) v = -1e30f;
        p[n][j] = v;
        mloc = fmaxf(mloc, v);
      }
    mloc = fmaxf(mloc, __shfl_xor(mloc, 16));
    mloc = fmaxf(mloc, __shfl_xor(mloc, 32));
    const float mn = fmaxf(m_run, mloc);
    const float sc = __expf(m_run - mn);
    m_run = mn;
    float ls = 0.f;
#pragma unroll
    for (int n = 0; n < 4; ++n)
#pragma unroll
      for (int j = 0; j < 4; ++j) { p[n][j] = __expf(p[n][j] - mn); ls += p[n][j]; }
    ls += __shfl_xor(ls, 16);
    ls += __shfl_xor(ls, 32);
    l_run = l_run * sc + ls;
    float scb[4];
#pragma unroll
    for (int j = 0; j < 4; ++j) scb[j] = __shfl(sc, lg * 4 + j);
#pragma unroll
    for (int n = 0; n < 4; ++n)
#pragma unroll
      for (int j = 0; j < 4; ++j) o[n][j] *= scb[j];
#pragma unroll
    for (int n = 0; n < 4; ++n)
#pragma unroll
      for (int j = 0; j < 4; ++j)
        psw[lr * 64 + ((n * 2 + (lg >> 1)) ^ sw) * 8 + (lg & 1) * 4 + j] =
            __float2bfloat16(p[n][j]);
    bf16x8 pa0 = *(const bf16x8*)(&psw[lr * 64 + ((lg) ^ sw) * 8]);
    bf16x8 pa1 = *(const bf16x8*)(&psw[lr * 64 + ((4 + lg) ^ sw) * 8]);
#pragma unroll
    for (int n = 0; n < 4; ++n) {
      const int vdh = n * 16 + lr;
      const int swv = (vdh & 7) ^ ((vdh >> 3) & 7);
      bf16x8 v0f = *(const bf16x8*)(vts[cur] + vdh * 64 + ((lg) ^ swv) * 8);
      bf16x8 v1f = *(const bf16x8*)(vts[cur] + vdh * 64 + ((4 + lg) ^ swv) * 8);
      o[n] = __builtin_amdgcn_mfma_f32_16x16x32_bf16(pa0, v0f, o[n], 0, 0, 0);
      o[n] = __builtin_amdgcn_mfma_f32_16x16x32_bf16(pa1, v1f, o[n], 0, 0, 0);
    }
  };

  for (int kvt = 0; kvt <= qhi; ++kvt) {
    const int nxt = cur ^ 1;
    const bool pf = (kvt < qhi);
    if (pf) {  // prefetch next K tile + V rows
      const int kv1 = (kvt + 1) * 64;
#pragma unroll
      for (int r = 0; r < 2; ++r) {
        int c = tid + r * 256, row = c >> 3, p = c & 7;
        GLD16(kb + (size_t)(kv1 + row) * rs + (p ^ (row & 7)) * 8, ks[nxt] + c * 8);
      }
      vr0 = *(const float4*)(vb + (size_t)(kv1 + 2 * vrow2) * rs + vseg * 8);
      vr1 = *(const float4*)(vb + (size_t)(kv1 + 2 * vrow2 + 1) * rs + vseg * 8);
    }
    process(qh0, qh1, kvt == qhi, m_hi, l_hi, o_hi, psh);
    if (kvt <= qlo) process(ql0, ql1, kvt == qlo, m_lo, l_lo, o_lo, psl);
    if (pf) {  // write V(t+1) regs -> vts[nxt] (vmcnt wait after compute)
      const unsigned short* u0 = (const unsigned short*)&vr0;
      const unsigned short* u1 = (const unsigned short*)&vr1;
#pragma unroll
      for (int i = 0; i < 8; ++i) {
        const int dh = vseg * 8 + i;
        const int phys = (vrow2 >> 2) ^ (dh & 7) ^ ((dh >> 3) & 7);
        unsigned int pk = (unsigned int)u0[i] | ((unsigned int)u1[i] << 16);
        *(unsigned int*)(vts[nxt] + dh * 64 + phys * 8 + 2 * (vrow2 & 3)) = pk;
      }
    }
    __syncthreads();
    cur = nxt;
  }
  const float linv_h = 1.0f / l_hi, linv_l = 1.0f / l_lo;
#pragma unroll
  for (int j = 0; j < 4; ++j) {
    const float lih = __shfl(linv_h, lg * 4 + j);
    const float lil = __shfl(linv_l, lg * 4 + j);
    size_t rowh = (size_t)b * 2048 + q0hi + w * 16 + lg * 4 + j;
    size_t rowl = (size_t)b * 2048 + q0lo + w * 16 + lg * 4 + j;
#pragma unroll
    for (int n = 0; n < 4; ++n) {
      float vh = o_hi[n][j] * lih, vl = o_lo[n][j] * lil;
      outp[rowh * 1024 + h * 64 + n * 16 + lr] = vh;
      outp[rowl * 1024 + h * 64 + n * 16 + lr] = vl;
      outb[rowh * 2048 + ob_off + h * 64 + n * 16 + lr] = __float2bfloat16(vh);
      outb[rowl * 2048 + ob_off + h * 64 + n * 16 + lr] = __float2bfloat16(vl);
    }
  }
}

extern "C" void kernel_launch(void* const* d_in, const int* in_sizes, int n_in,
                              void* d_out, int out_size, void* d_ws, size_t ws_size,
                              hipStream_t stream) {
  const float* x     = (const float*)d_in[0];
  const float* Wqkv0 = (const float*)d_in[1];
  const float* bqkv0 = (const float*)d_in[2];
  const float* Wqkv1 = (const float*)d_in[3];
  const float* bqkv1 = (const float*)d_in[4];
  const float* Wg    = (const float*)d_in[5];
  const float* bg    = (const float*)d_in[6];
  const float* Wo    = (const float*)d_in[7];
  const float* bo    = (const float*)d_in[8];
  float* out = (float*)d_out;

  char* ws = (char*)d_ws;
  __hip_bfloat16* xb   = (__hip_bfloat16*)(ws);              // 8 MB (x_bf16 -> residb -> preout)
  __hip_bfloat16* qkv  = (__hip_bfloat16*)(ws + 8388608);    // 24 MB (qkv0 then qkv1)
  float*          pred = (float*)(ws + 33554432);            // 16 MB
  float*          corr = (float*)(ws + 50331648);            // 16 MB
  __hip_bfloat16* catb = (__hip_bfloat16*)(ws + 67108864);   // 16 MB [pred | corr] bf16
  __hip_bfloat16* Wt0  = (__hip_bfloat16*)(ws + 83886080);   // 6 MB
  __hip_bfloat16* Wt1  = (__hip_bfloat16*)(ws + 90177536);   // 6 MB
  __hip_bfloat16* Wgt  = (__hip_bfloat16*)(ws + 96468992);   // 4 MB
  __hip_bfloat16* Wot  = (__hip_bfloat16*)(ws + 100663296);  // 2 MB  (total ~98 MB)

  dim3 tb(32, 8);
  transpose_cast<<<dim3(3072 / 32, 1024 / 32), tb, 0, stream>>>(Wqkv0, Wt0, 1024, 3072);
  transpose_cast<<<dim3(3072 / 32, 1024 / 32), tb, 0, stream>>>(Wqkv1, Wt1, 1024, 3072);
  transpose_cast<<<dim3(1024 / 32, 2048 / 32), tb, 0, stream>>>(Wg, Wgt, 2048, 1024);
  transpose_cast<<<dim3(1024 / 32, 1024 / 32), tb, 0, stream>>>(Wo, Wot, 1024, 1024);
  cast_f32_bf16<<<4096, 256, 0, stream>>>(x, xb);

  // qkv0 = x @ Wqkv0 + b  (256^2 triple-buffered)
  gemm256_bf16<<<dim3(12, 16), 512, 0, stream>>>(xb, Wt0, bqkv0, qkv, 4096, 3072, 1024);
  attn_kernel<<<dim3(16, 16, 2), 256, 0, stream>>>(qkv, pred, catb, 0);
  resid_cast<<<4096, 256, 0, stream>>>(x, pred, xb);
  // qkv1 = (x - pred) @ Wqkv1 + b
  gemm256_bf16<<<dim3(12, 16), 512, 0, stream>>>(xb, Wt1, bqkv1, qkv, 4096, 3072, 1024);
  attn_kernel<<<dim3(16, 16, 2), 256, 0, stream>>>(qkv, corr, catb, 1024);
  // preout = sigmoid(cat @ Wg + bg) * corr + pred   (into xb)
  gemm_bf16<1><<<dim3(8, 32), 256, 0, stream>>>(catb, Wgt, bg, (void*)xb,
                                                corr, pred, 4096, 1024, 2048);
  // out = preout @ Wo + bo (fp32)
  gemm_bf16<2><<<dim3(8, 32), 256, 0, stream>>>(xb, Wot, bo, (void*)out,
                                                nullptr, nullptr, 4096, 1024, 1024);
}

// Round 17
// 302.176 us; speedup vs baseline: 1.0824x; 1.0824x over previous
//
#include <hip/hip_runtime.h>
#include <hip/hip_bf16.h>

// BoostedCausalAttention: bf16 MFMA pipeline
// B=2 T=2048 D=1024 H=16 DH=64, fp32 in/out, bf16 internal compute.
// R6 589 -> R8 swizzle 475 -> R9 pairing 352.9 -> R13/14 GEMM dbuf ->
// R15 swapped-QK softmax 309.3 (attn 72.0).
// R16 (part-reverted): gemm256 96KB-LDS = 1 block/CU + 192-block grid ->
//   qkv 43->58us REGRESSION (occupancy, not schedule). Attn V5b (packed-V,
//   dual fp32+bf16 out, corr_cast eliminated) neutral-to-positive: KEPT.
// R17: qkv back to verified 128^2 dbuf gemm_bf16<0> (~40us, 3 blocks/CU).
//   Lesson: check blocks/CU x CU-coverage before tile-size changes.

typedef __bf16 bf16x8 __attribute__((ext_vector_type(8)));
typedef float f32x4 __attribute__((ext_vector_type(4)));

__device__ __forceinline__ unsigned short f2bf(float f) {
  union { __hip_bfloat16 h; unsigned short u; } cv;
  cv.h = __float2bfloat16(f);
  return cv.u;
}

#define GLD16(gp, lp) __builtin_amdgcn_global_load_lds(                      \
    (const __attribute__((address_space(1))) void*)(gp),                     \
    (__attribute__((address_space(3))) void*)(lp), 16, 0, 0)

// ---------------- transpose + cast: fp32 [R][C] -> bf16 [C][R] --------------
__global__ __launch_bounds__(256) void transpose_cast(
    const float* __restrict__ in, __hip_bfloat16* __restrict__ out, int R, int C) {
  __shared__ float t[32][33];
  int bx = blockIdx.x * 32, by = blockIdx.y * 32;
  int tx = threadIdx.x, ty = threadIdx.y;
#pragma unroll
  for (int i = 0; i < 32; i += 8)
    t[ty + i][tx] = in[(size_t)(by + ty + i) * C + bx + tx];
  __syncthreads();
#pragma unroll
  for (int i = 0; i < 32; i += 8)
    out[(size_t)(bx + ty + i) * R + by + tx] = __float2bfloat16(t[tx][ty + i]);
}

// ---------------- cast x -> bf16 (vec4) ------------------------------------
__global__ __launch_bounds__(256) void cast_f32_bf16(
    const float* __restrict__ in, __hip_bfloat16* __restrict__ out) {
  size_t e = ((size_t)blockIdx.x * blockDim.x + threadIdx.x) * 4;
  float4 v = *(const float4*)(in + e);
  ushort4 o;
  o.x = f2bf(v.x); o.y = f2bf(v.y); o.z = f2bf(v.z); o.w = f2bf(v.w);
  *(ushort4*)((unsigned short*)out + e) = o;
}

// --- residb = bf16(x - pred)  (catb pred-half written by attn) --------------
__global__ __launch_bounds__(256) void resid_cast(
    const float* __restrict__ x, const float* __restrict__ pred,
    __hip_bfloat16* __restrict__ residb) {
  size_t e = ((size_t)blockIdx.x * blockDim.x + threadIdx.x) * 4;
  float4 xv = *(const float4*)(x + e);
  float4 pv = *(const float4*)(pred + e);
  ushort4 rb;
  rb.x = f2bf(xv.x - pv.x); rb.y = f2bf(xv.y - pv.y);
  rb.z = f2bf(xv.z - pv.z); rb.w = f2bf(xv.w - pv.w);
  *(ushort4*)((unsigned short*)residb + e) = rb;
}

// ------- bf16 MFMA GEMM, 128x128 tile, BK=32, double-buffered (R13) ---------
// EPI 0: out bf16 = acc+bias; EPI 1: bf16 sigmoid(acc+bias)*aux0+aux1;
// EPI 2: fp32 acc+bias.
template <int EPI>
__global__ __launch_bounds__(256) void gemm_bf16(
    const __hip_bfloat16* __restrict__ A, const __hip_bfloat16* __restrict__ Bt,
    const float* __restrict__ bias, void* __restrict__ outp,
    const float* __restrict__ aux0, const float* __restrict__ aux1,
    int M, int N, int K) {
  __shared__ __hip_bfloat16 As[2][128 * 32];
  __shared__ __hip_bfloat16 Bs[2][128 * 32];
  const int tid = threadIdx.x;
  const int lane = tid & 63, wid = tid >> 6;
  const int wr = wid >> 1, wc = wid & 1;
  const int lr = lane & 15, lk = (lane >> 4) * 8;
  const size_t brow = (size_t)blockIdx.y * 128, bcol = (size_t)blockIdx.x * 128;
  f32x4 acc[4][4] = {};
#pragma unroll
  for (int r = 0; r < 2; ++r) {
    int c = tid + r * 256;
    GLD16(A + (brow + (size_t)(c >> 2)) * K + (c & 3) * 8, As[0] + c * 8);
    GLD16(Bt + (bcol + (size_t)(c >> 2)) * K + (c & 3) * 8, Bs[0] + c * 8);
  }
  __syncthreads();
  int cur = 0;
  for (int k0 = 0; k0 < K; k0 += 32) {
    const int nxt = cur ^ 1;
    if (k0 + 32 < K) {
#pragma unroll
      for (int r = 0; r < 2; ++r) {
        int c = tid + r * 256;
        GLD16(A + (brow + (size_t)(c >> 2)) * K + k0 + 32 + (c & 3) * 8,
              As[nxt] + c * 8);
        GLD16(Bt + (bcol + (size_t)(c >> 2)) * K + k0 + 32 + (c & 3) * 8,
              Bs[nxt] + c * 8);
      }
    }
    bf16x8 a[4], b[4];
#pragma unroll
    for (int m = 0; m < 4; ++m)
      a[m] = *(const bf16x8*)(As[cur] + (wr * 64 + m * 16 + lr) * 32 + lk);
#pragma unroll
    for (int n = 0; n < 4; ++n)
      b[n] = *(const bf16x8*)(Bs[cur] + (wc * 64 + n * 16 + lr) * 32 + lk);
#pragma unroll
    for (int m = 0; m < 4; ++m)
#pragma unroll
      for (int n = 0; n < 4; ++n)
        acc[m][n] = __builtin_amdgcn_mfma_f32_16x16x32_bf16(a[m], b[n], acc[m][n], 0, 0, 0);
    __syncthreads();
    cur = nxt;
  }
  const int r0 = (lane >> 4) * 4, cn = lane & 15;
#pragma unroll
  for (int m = 0; m < 4; ++m)
#pragma unroll
    for (int n = 0; n < 4; ++n) {
      size_t col = bcol + wc * 64 + n * 16 + cn;
      float bv = bias[col];
#pragma unroll
      for (int j = 0; j < 4; ++j) {
        size_t row = brow + wr * 64 + m * 16 + r0 + j;
        float v = acc[m][n][j] + bv;
        if constexpr (EPI == 1) {
          float g = 1.0f / (1.0f + __expf(-v));
          float val = g * aux0[row * N + col] + aux1[row * N + col];
          ((__hip_bfloat16*)outp)[row * N + col] = __float2bfloat16(val);
        } else if constexpr (EPI == 2) {
          ((float*)outp)[row * N + col] = v;
        } else {
          ((__hip_bfloat16*)outp)[row * N + col] = __float2bfloat16(v);
        }
      }
    }
}

// ------- causal flash attention V5b (swapped QK^T, b32 V-stage, dual out) ---
// R15-verified structure + R16-verified packed-V/dual-output. fp32 outp
// (stride 1024) + bf16 outb (stride 2048, +ob_off) for catb.
__global__ __launch_bounds__(256) void attn_kernel(
    const __hip_bfloat16* __restrict__ qkv, float* __restrict__ outp,
    __hip_bfloat16* __restrict__ outb, int ob_off) {
  const int b = blockIdx.z, h = blockIdx.y, qtp = blockIdx.x;
  const int qlo = qtp, qhi = 31 - qtp;
  const int q0lo = qlo * 64, q0hi = qhi * 64;
  __shared__ __hip_bfloat16 ks[2][64 * 64];
  __shared__ __hip_bfloat16 vts[2][64 * 64];  // V^T [dh][kv], swizzled
  __shared__ __hip_bfloat16 qps[8192];        // Q_hi|Q_lo staging -> ps_hi|ps_lo
  const int tid = threadIdx.x, lane = tid & 63, w = tid >> 6;
  const int lr = lane & 15, lg = lane >> 4;
  const int sw = lr & 7;
  const size_t rs = 3072;
  const __hip_bfloat16* qbh = qkv + ((size_t)b * 2048 + q0hi) * rs + h * 64;
  const __hip_bfloat16* qbl = qkv + ((size_t)b * 2048 + q0lo) * rs + h * 64;
  const __hip_bfloat16* kb = qkv + (size_t)b * 2048 * rs + 1024 + h * 64;
  const __hip_bfloat16* vb = qkv + (size_t)b * 2048 * rs + 2048 + h * 64;

  const int vrow2 = tid >> 3, vseg = tid & 7;  // V staging: kv pair, dh seg
  float4 vr0, vr1;
#pragma unroll
  for (int r = 0; r < 2; ++r) {
    int c = tid + r * 256, row = c >> 3, p = c & 7;
    GLD16(qbh + (size_t)row * rs + (p ^ (row & 7)) * 8, qps + c * 8);
    GLD16(qbl + (size_t)row * rs + (p ^ (row & 7)) * 8, qps + 4096 + c * 8);
    GLD16(kb + (size_t)row * rs + (p ^ (row & 7)) * 8, ks[0] + c * 8);
  }
  vr0 = *(const float4*)(vb + (size_t)(2 * vrow2) * rs + vseg * 8);
  vr1 = *(const float4*)(vb + (size_t)(2 * vrow2 + 1) * rs + vseg * 8);
  __syncthreads();
  const int qrow = w * 16 + lr;
  const bf16x8 qh0 = *(const bf16x8*)(qps + qrow * 64 + ((lg) ^ (qrow & 7)) * 8);
  const bf16x8 qh1 = *(const bf16x8*)(qps + qrow * 64 + ((4 + lg) ^ (qrow & 7)) * 8);
  const bf16x8 ql0 = *(const bf16x8*)(qps + 4096 + qrow * 64 + ((lg) ^ (qrow & 7)) * 8);
  const bf16x8 ql1 = *(const bf16x8*)(qps + 4096 + qrow * 64 + ((4 + lg) ^ (qrow & 7)) * 8);
  {
    const unsigned short* u0 = (const unsigned short*)&vr0;
    const unsigned short* u1 = (const unsigned short*)&vr1;
#pragma unroll
    for (int i = 0; i < 8; ++i) {
      const int dh = vseg * 8 + i;
      const int phys = (vrow2 >> 2) ^ (dh & 7) ^ ((dh >> 3) & 7);
      unsigned int pk = (unsigned int)u0[i] | ((unsigned int)u1[i] << 16);
      *(unsigned int*)(vts[0] + dh * 64 + phys * 8 + 2 * (vrow2 & 3)) = pk;
    }
  }
  __syncthreads();  // Q frags in regs; qps now free for ps

  __hip_bfloat16* psh = qps + w * 1024;         // wave-private, hi tile
  __hip_bfloat16* psl = qps + 4096 + w * 1024;  // wave-private, lo tile
  float m_hi = -1e30f, l_hi = 0.f, m_lo = -1e30f, l_lo = 0.f;
  f32x4 o_hi[4] = {}, o_lo[4] = {};
  int cur = 0;

  auto process = [&](const bf16x8& qa0, const bf16x8& qa1, bool diag,
                     float& m_run, float& l_run, f32x4* o, __hip_bfloat16* psw) {
    f32x4 s4[4] = {};
#pragma unroll
    for (int n = 0; n < 4; ++n) {
      const int kr = n * 16 + lr;
      bf16x8 k0f = *(const bf16x8*)(ks[cur] + kr * 64 + ((lg) ^ sw) * 8);
      bf16x8 k1f = *(const bf16x8*)(ks[cur] + kr * 64 + ((4 + lg) ^ sw) * 8);
      s4[n] = __builtin_amdgcn_mfma_f32_16x16x32_bf16(k0f, qa0, s4[n], 0, 0, 0);
      s4[n] = __builtin_amdgcn_mfma_f32_16x16x32_bf16(k1f, qa1, s4[n], 0, 0, 0);
    }
    float p[4][4];
    float mloc = -1e30f;
#pragma unroll
    for (int n = 0; n < 4; ++n)
#pragma unroll
      for (int j = 0; j < 4; ++j) {
        float v = s4[n][j] * 0.125f;
        if (diag && (n * 16 + lg * 4 + j) > (w * 16 + lr)) v = -1e30f;
        p[n][j] = v;
        mloc = fmaxf(mloc, v);
      }
    mloc = fmaxf(mloc, __shfl_xor(mloc, 16));
    mloc = fmaxf(mloc, __shfl_xor(mloc, 32));
    const float mn = fmaxf(m_run, mloc);
    const float sc = __expf(m_run - mn);
    m_run = mn;
    float ls = 0.f;
#pragma unroll
    for (int n = 0; n < 4; ++n)
#pragma unroll
      for (int j = 0; j < 4; ++j) { p[n][j] = __expf(p[n][j] - mn); ls += p[n][j]; }
    ls += __shfl_xor(ls, 16);
    ls += __shfl_xor(ls, 32);
    l_run = l_run * sc + ls;
    float scb[4];
#pragma unroll
    for (int j = 0; j < 4; ++j) scb[j] = __shfl(sc, lg * 4 + j);
#pragma unroll
    for (int n = 0; n < 4; ++n)
#pragma unroll
      for (int j = 0; j < 4; ++j) o[n][j] *= scb[j];
#pragma unroll
    for (int n = 0; n < 4; ++n)
#pragma unroll
      for (int j = 0; j < 4; ++j)
        psw[lr * 64 + ((n * 2 + (lg >> 1)) ^ sw) * 8 + (lg & 1) * 4 + j] =
            __float2bfloat16(p[n][j]);
    bf16x8 pa0 = *(const bf16x8*)(&psw[lr * 64 + ((lg) ^ sw) * 8]);
    bf16x8 pa1 = *(const bf16x8*)(&psw[lr * 64 + ((4 + lg) ^ sw) * 8]);
#pragma unroll
    for (int n = 0; n < 4; ++n) {
      const int vdh = n * 16 + lr;
      const int swv = (vdh & 7) ^ ((vdh >> 3) & 7);
      bf16x8 v0f = *(const bf16x8*)(vts[cur] + vdh * 64 + ((lg) ^ swv) * 8);
      bf16x8 v1f = *(const bf16x8*)(vts[cur] + vdh * 64 + ((4 + lg) ^ swv) * 8);
      o[n] = __builtin_amdgcn_mfma_f32_16x16x32_bf16(pa0, v0f, o[n], 0, 0, 0);
      o[n] = __builtin_amdgcn_mfma_f32_16x16x32_bf16(pa1, v1f, o[n], 0, 0, 0);
    }
  };

  for (int kvt = 0; kvt <= qhi; ++kvt) {
    const int nxt = cur ^ 1;
    const bool pf = (kvt < qhi);
    if (pf) {
      const int kv1 = (kvt + 1) * 64;
#pragma unroll
      for (int r = 0; r < 2; ++r) {
        int c = tid + r * 256, row = c >> 3, p = c & 7;
        GLD16(kb + (size_t)(kv1 + row) * rs + (p ^ (row & 7)) * 8, ks[nxt] + c * 8);
      }
      vr0 = *(const float4*)(vb + (size_t)(kv1 + 2 * vrow2) * rs + vseg * 8);
      vr1 = *(const float4*)(vb + (size_t)(kv1 + 2 * vrow2 + 1) * rs + vseg * 8);
    }
    process(qh0, qh1, kvt == qhi, m_hi, l_hi, o_hi, psh);
    if (kvt <= qlo) process(ql0, ql1, kvt == qlo, m_lo, l_lo, o_lo, psl);
    if (pf) {
      const unsigned short* u0 = (const unsigned short*)&vr0;
      const unsigned short* u1 = (const unsigned short*)&vr1;
#pragma unroll
      for (int i = 0; i < 8; ++i) {
        const int dh = vseg * 8 + i;
        const int phys = (vrow2 >> 2) ^ (dh & 7) ^ ((dh >> 3) & 7);
        unsigned int pk = (unsigned int)u0[i] | ((unsigned int)u1[i] << 16);
        *(unsigned int*)(vts[nxt] + dh * 64 + phys * 8 + 2 * (vrow2 & 3)) = pk;
      }
    }
    __syncthreads();
    cur = nxt;
  }
  const float linv_h = 1.0f / l_hi, linv_l = 1.0f / l_lo;
#pragma unroll
  for (int j = 0; j < 4; ++j) {
    const float lih = __shfl(linv_h, lg * 4 + j);
    const float lil = __shfl(linv_l, lg * 4 + j);
    size_t rowh = (size_t)b * 2048 + q0hi + w * 16 + lg * 4 + j;
    size_t rowl = (size_t)b * 2048 + q0lo + w * 16 + lg * 4 + j;
#pragma unroll
    for (int n = 0; n < 4; ++n) {
      float vh = o_hi[n][j] * lih, vl = o_lo[n][j] * lil;
      outp[rowh * 1024 + h * 64 + n * 16 + lr] = vh;
      outp[rowl * 1024 + h * 64 + n * 16 + lr] = vl;
      outb[rowh * 2048 + ob_off + h * 64 + n * 16 + lr] = __float2bfloat16(vh);
      outb[rowl * 2048 + ob_off + h * 64 + n * 16 + lr] = __float2bfloat16(vl);
    }
  }
}

extern "C" void kernel_launch(void* const* d_in, const int* in_sizes, int n_in,
                              void* d_out, int out_size, void* d_ws, size_t ws_size,
                              hipStream_t stream) {
  const float* x     = (const float*)d_in[0];
  const float* Wqkv0 = (const float*)d_in[1];
  const float* bqkv0 = (const float*)d_in[2];
  const float* Wqkv1 = (const float*)d_in[3];
  const float* bqkv1 = (const float*)d_in[4];
  const float* Wg    = (const float*)d_in[5];
  const float* bg    = (const float*)d_in[6];
  const float* Wo    = (const float*)d_in[7];
  const float* bo    = (const float*)d_in[8];
  float* out = (float*)d_out;

  char* ws = (char*)d_ws;
  __hip_bfloat16* xb   = (__hip_bfloat16*)(ws);              // 8 MB (x_bf16 -> residb -> preout)
  __hip_bfloat16* qkv  = (__hip_bfloat16*)(ws + 8388608);    // 24 MB (qkv0 then qkv1)
  float*          pred = (float*)(ws + 33554432);            // 16 MB
  float*          corr = (float*)(ws + 50331648);            // 16 MB
  __hip_bfloat16* catb = (__hip_bfloat16*)(ws + 67108864);   // 16 MB [pred | corr] bf16
  __hip_bfloat16* Wt0  = (__hip_bfloat16*)(ws + 83886080);   // 6 MB
  __hip_bfloat16* Wt1  = (__hip_bfloat16*)(ws + 90177536);   // 6 MB
  __hip_bfloat16* Wgt  = (__hip_bfloat16*)(ws + 96468992);   // 4 MB
  __hip_bfloat16* Wot  = (__hip_bfloat16*)(ws + 100663296);  // 2 MB  (total ~98 MB)

  dim3 tb(32, 8);
  transpose_cast<<<dim3(3072 / 32, 1024 / 32), tb, 0, stream>>>(Wqkv0, Wt0, 1024, 3072);
  transpose_cast<<<dim3(3072 / 32, 1024 / 32), tb, 0, stream>>>(Wqkv1, Wt1, 1024, 3072);
  transpose_cast<<<dim3(1024 / 32, 2048 / 32), tb, 0, stream>>>(Wg, Wgt, 2048, 1024);
  transpose_cast<<<dim3(1024 / 32, 1024 / 32), tb, 0, stream>>>(Wo, Wot, 1024, 1024);
  cast_f32_bf16<<<4096, 256, 0, stream>>>(x, xb);

  // qkv0 = x @ Wqkv0 + b  (128^2 dbuf, verified)
  gemm_bf16<0><<<dim3(24, 32), 256, 0, stream>>>(xb, Wt0, bqkv0, (void*)qkv,
                                                 nullptr, nullptr, 4096, 3072, 1024);
  attn_kernel<<<dim3(16, 16, 2), 256, 0, stream>>>(qkv, pred, catb, 0);
  resid_cast<<<4096, 256, 0, stream>>>(x, pred, xb);
  // qkv1 = (x - pred) @ Wqkv1 + b
  gemm_bf16<0><<<dim3(24, 32), 256, 0, stream>>>(xb, Wt1, bqkv1, (void*)qkv,
                                                 nullptr, nullptr, 4096, 3072, 1024);
  attn_kernel<<<dim3(16, 16, 2), 256, 0, stream>>>(qkv, corr, catb, 1024);
  // preout = sigmoid(cat @ Wg + bg) * corr + pred   (into xb)
  gemm_bf16<1><<<dim3(8, 32), 256, 0, stream>>>(catb, Wgt, bg, (void*)xb,
                                                corr, pred, 4096, 1024, 2048);
  // out = preout @ Wo + bo (fp32)
  gemm_bf16<2><<<dim3(8, 32), 256, 0, stream>>>(xb, Wot, bo, (void*)out,
                                                nullptr, nullptr, 4096, 1024, 1024);
}